// Round 11
// baseline (448.875 us; speedup 1.0000x reference)
//
#include <hip/hip_runtime.h>
#include <stdint.h>

namespace {

constexpr int DIM  = 180;
constexpr int LL   = 14336;
constexpr int B    = 16;
constexpr int T    = 56;      // tokens per block (8 windows, 4 window-pairs)
constexpr int NCH  = 256;
constexpr int EQKV = 540;

constexpr int QTS  = 392;     // qt row stride u16 (784B: 16B-mult, 49 granules = odd)
constexpr int KOFF = 192;     // k region offset within qt row
constexpr int QT_U16  = T * QTS;          // 21952
constexpr int VT_U16  = 24 * 512;         // 12288  (4 wpair x 6 h x 32 d x 16 j)
constexpr int XSS     = 200;
constexpr int XS_U16  = 32 * XSS;         // 6400
constexpr int LDS_U16 = QT_U16 + VT_U16 + XS_U16;  // 40640 u16 = 81280 B

typedef __attribute__((ext_vector_type(8))) short bf16x8;
typedef __attribute__((ext_vector_type(4))) float f32x4;

union Frag { bf16x8 v; uint32_t u[4]; unsigned short s[8]; };

__device__ __forceinline__ unsigned short f2b(float f) {
  uint32_t u = __builtin_bit_cast(uint32_t, f);
  u = (u + 0x7fffu + ((u >> 16) & 1u)) >> 16;   // RNE
  return (unsigned short)u;
}
__device__ __forceinline__ uint32_t pack2(float lo, float hi) {
  return (uint32_t)f2b(lo) | ((uint32_t)f2b(hi) << 16);
}
__device__ __forceinline__ f32x4 zero4() { f32x4 z = {0.f,0.f,0.f,0.f}; return z; }

} // namespace

// ---- prep: wqkv_b[576][192] natural cols; wo_h[192][192] cols = 32h+d -----
__global__ __launch_bounds__(1024) void la_prep(
    const float* __restrict__ Wq, const float* __restrict__ Wkv,
    const float* __restrict__ Wo, unsigned short* __restrict__ wqkv_b,
    unsigned short* __restrict__ wo_h) {
  const int idx = (int)(blockIdx.x * 1024 + threadIdx.x);
  if (idx < 576 * 192) {
    const int e = idx / 192, c = idx - e * 192;
    float v = 0.f;
    if (e < EQKV && c < DIM)
      v = (e < DIM) ? Wq[e * DIM + c] : Wkv[(size_t)(e - DIM) * DIM + c];
    wqkv_b[idx] = f2b(v);
  } else {
    const int k = idx - 576 * 192;
    if (k < 192 * 192) {
      const int o = k / 192, cc = k - o * 192;
      const int h = cc >> 5, d = cc & 31;
      float v = 0.f;
      if (o < DIM && d < 30) v = Wo[o * DIM + h * 30 + d];
      wo_h[k] = f2b(v);
    }
  }
}

// ---- fused main: 512 threads, T=56, 2 blocks/CU, MFMA attention -----------
__global__ __launch_bounds__(512, 4) void la_main(
    const float* __restrict__ fmap, const unsigned short* __restrict__ wqkv,
    const unsigned short* __restrict__ wo_h, const float* __restrict__ bo,
    float* __restrict__ out) {
  __shared__ __align__(16) unsigned short lds[LDS_U16];
  unsigned short* qt = lds;                     // [56][392]: q 32h+d | k 192+32h+d
  unsigned short* vt = lds + QT_U16;            // [4][6][32][16]
  unsigned short* xs = lds + QT_U16 + VT_U16;   // [32][200]

  const int tid  = (int)threadIdx.x;
  const int wave = tid >> 6;
  const int lane = tid & 63;
  const int l15  = lane & 15;
  const int g    = lane >> 4;

  const int bi    = (int)blockIdx.x;
  const int b     = bi >> 8;
  const int chunk = bi & 255;
  const int t0    = chunk * T;

  const unsigned short* wA = wqkv + (size_t)l15 * 192 + g * 8;

  // zero-init vt: unwritten slots (j=14,15; d>=30) must be 0.0, not junk,
  // because PV multiplies them by P=0 and 0*NaN-junk = NaN. (R10 bug)
#pragma unroll
  for (int it = 0; it < 3; ++it)
    ((uint4*)vt)[tid + it * 512] = make_uint4(0u, 0u, 0u, 0u);

  // ================= stage 1: qkv = Wqkv @ x ===============================
#pragma unroll
  for (int ph = 0; ph < 2; ++ph) {
    const int tb = ph * 32;
#pragma unroll
    for (int it = 0; it < 3; ++it) {
      const int idx = tid + it * 512;
      const int c  = idx >> 3;
      const int tq = (idx & 7) * 4;
      float4 v = {0.f, 0.f, 0.f, 0.f};
      if (c < DIM && (tb + tq) < T)
        v = *(const float4*)(fmap + (size_t)(b * DIM + c) * LL + t0 + tb + tq);
      unsigned short* xr = xs + tq * XSS + c;
      xr[0 * XSS] = f2b(v.x);
      xr[1 * XSS] = f2b(v.y);
      xr[2 * XSS] = f2b(v.z);
      xr[3 * XSS] = f2b(v.w);
    }
    bf16x8 An[6];
#pragma unroll
    for (int ks = 0; ks < 6; ++ks)
      An[ks] = *(const bf16x8*)(wA + (size_t)(wave * 16) * 192 + ks * 32);
    __syncthreads();
    bf16x8 b0[6], b1[6];
#pragma unroll
    for (int ks = 0; ks < 6; ++ks) {
      b0[ks] = *(const bf16x8*)(xs + l15 * XSS + ks * 32 + g * 8);
      b1[ks] = *(const bf16x8*)(xs + (16 + l15) * XSS + ks * 32 + g * 8);
    }
    int mt = wave;
#pragma unroll 5
    for (int it = 0; it < 5; ++it) {
      if (mt < 36) {
        bf16x8 A[6];
#pragma unroll
        for (int ks = 0; ks < 6; ++ks) A[ks] = An[ks];
        const int mtn = mt + 8;
        if (mtn < 36) {
#pragma unroll
          for (int ks = 0; ks < 6; ++ks)
            An[ks] = *(const bf16x8*)(wA + (size_t)(mtn * 16) * 192 + ks * 32);
        }
        f32x4 a0 = zero4(), a1 = zero4();
#pragma unroll
        for (int ks = 0; ks < 6; ++ks) {
          a0 = __builtin_amdgcn_mfma_f32_16x16x32_bf16(A[ks], b0[ks], a0, 0, 0, 0);
          a1 = __builtin_amdgcn_mfma_f32_16x16x32_bf16(A[ks], b1[ks], a1, 0, 0, 0);
        }
        // writeback: col=t=l15, row e=g*4+r; q/k head-padded, v transposed
        const int e0 = mt * 16 + g * 4;
        if (e0 < EQKV) {
#pragma unroll
          for (int nt = 0; nt < 2; ++nt) {
            const f32x4 A4 = nt ? a1 : a0;
            const int t = tb + nt * 16 + l15;
            if (t < T) {
              if (e0 < 360) {
                unsigned short* qrow = qt + t * QTS;
#pragma unroll
                for (int pr = 0; pr < 2; ++pr) {
                  const int e = e0 + 2 * pr;   // even: never crosses a 30-bnd
                  int col;
                  if (e < 180) { const int h = e / 30; col = e + 2 * h; }
                  else { const int rr = e - 180; const int h = rr / 30; col = KOFF + rr + 2 * h; }
                  *(uint32_t*)(qrow + col) = pack2(A4[2 * pr], A4[2 * pr + 1]);
                }
              } else {
                const int wp = t / 14, jp = t - wp * 14;
#pragma unroll
                for (int r = 0; r < 4; ++r) {
                  const int rr = e0 - 360 + r;
                  const int h = rr / 30, d = rr - 30 * h;
                  vt[((wp * 6 + h) << 9) + (d << 4) + jp] = f2b(A4[r]);
                }
              }
            }
          }
        }
      }
      mt += 8;
    }
    __syncthreads();
  }

  // ================= stage 2: MFMA windowed attention ======================
  // 24 units (wpair x head), 3 per wave. S[j][i] = K·Q^T via 16x16x32;
  // masked softmax across row-groups (shfl 16/32); PV via P^T x vt.
  const float scale = 0.18257418583505536f;  // 30^-0.5
#pragma unroll
  for (int u = 0; u < 3; ++u) {
    const int unit = wave * 3 + u;
    const int wp = unit / 6, h = unit - wp * 6;
    const int twb = wp * 14;
    const int arow = twb + l15;
    const unsigned short* rowp = qt + ((arow < T) ? arow : (T - 1)) * QTS;
    Frag A, Bq;
    A.v  = *(const bf16x8*)(rowp + KOFF + (h << 5) + (g << 3));  // k rows
    Bq.v = *(const bf16x8*)(rowp + (h << 5) + (g << 3));         // q cols
    if (g == 3) { A.u[3] = 0; Bq.u[3] = 0; }  // zero k=30,31 BOTH sides (pads junk)
    const f32x4 s = __builtin_amdgcn_mfma_f32_16x16x32_bf16(A.v, Bq.v, zero4(), 0, 0, 0);
    // lane: col i = l15 (q token), rows j = 4g+r
    float p[4];
    float mx = -3e38f;
#pragma unroll
    for (int r = 0; r < 4; ++r) {
      const int j = (g << 2) + r;
      const bool valid = (l15 < 7) ? (j < 7) : (j >= 7 && j < 14);
      p[r] = valid ? s[r] : -3e38f;
      mx = fmaxf(mx, p[r]);
    }
    mx = fmaxf(mx, __shfl_xor(mx, 16));
    mx = fmaxf(mx, __shfl_xor(mx, 32));
    float sum = 0.f;
#pragma unroll
    for (int r = 0; r < 4; ++r) {
      p[r] = __expf(scale * (p[r] - mx));
      sum += p[r];
    }
    sum += __shfl_xor(sum, 16);
    sum += __shfl_xor(sum, 32);
    const float inv = 1.f / sum;
#pragma unroll
    for (int r = 0; r < 4; ++r) p[r] *= inv;
    // redistribute P (col-layout) -> A-layout (k = j = 8g+e) via shfl
    const uint32_t pk0 = pack2(p[0], p[1]);
    const uint32_t pk1 = pack2(p[2], p[3]);
    const int s0 = l15 + ((g & 1) << 5);
    Frag PA;
    PA.u[0] = __shfl(pk0, s0);
    PA.u[1] = __shfl(pk1, s0);
    PA.u[2] = __shfl(pk0, s0 + 16);
    PA.u[3] = __shfl(pk1, s0 + 16);
    if (g >= 2) { PA.u[0] = 0; PA.u[1] = 0; PA.u[2] = 0; PA.u[3] = 0; }
    // PV: B = vt[d][j] (lane=d, k=j); j>=14 P=0 x vt=0; d>=30 vt rows are 0
    const unsigned short* vtb = vt + ((wp * 6 + h) << 9);
    const bf16x8 V0 = *(const bf16x8*)(vtb + (l15 << 4) + (g << 3));
    const bf16x8 V1 = *(const bf16x8*)(vtb + ((16 + l15) << 4) + (g << 3));
    const f32x4 o0 = __builtin_amdgcn_mfma_f32_16x16x32_bf16(PA.v, V0, zero4(), 0, 0, 0);
    const f32x4 o1 = __builtin_amdgcn_mfma_f32_16x16x32_bf16(PA.v, V1, zero4(), 0, 0, 0);
    // store: col d = l15 (+16), rows i = 4g+r -> qt q-region [32h + d]
    // o1 at l15>=14 is exactly 0 (vt rows d=30,31 zeroed) -> cleans pad slots
#pragma unroll
    for (int r = 0; r < 4; ++r) {
      const int irow = (g << 2) + r;
      if (irow < 14) {
        unsigned short* orow = qt + (twb + irow) * QTS + (h << 5);
        orow[l15] = f2b(o0[r]);
        orow[16 + l15] = f2b(o1[r]);
      }
    }
  }
  __syncthreads();

  // ================= stage 3: y = Wo @ att + bo ============================
  {
    const int n3 = wave & 3;
    const int m3 = (wave >> 2) * 6;
    const int tc  = n3 * 16 + l15;
    const int trd = (tc < T) ? tc : (T - 1);
    bf16x8 bq[6];
#pragma unroll
    for (int ks = 0; ks < 6; ++ks)
      bq[ks] = *(const bf16x8*)(qt + trd * QTS + ks * 32 + g * 8);
    const unsigned short* wO = wo_h + (size_t)l15 * 192 + g * 8;
    bf16x8 An[6];
#pragma unroll
    for (int ks = 0; ks < 6; ++ks)
      An[ks] = *(const bf16x8*)(wO + (size_t)(m3 * 16) * 192 + ks * 32);
#pragma unroll 6
    for (int k6 = 0; k6 < 6; ++k6) {
      const int m = m3 + k6;
      bf16x8 A[6];
#pragma unroll
      for (int ks = 0; ks < 6; ++ks) A[ks] = An[ks];
      if (k6 < 5) {
#pragma unroll
        for (int ks = 0; ks < 6; ++ks)
          An[ks] = *(const bf16x8*)(wO + (size_t)((m + 1) * 16) * 192 + ks * 32);
      }
      f32x4 acc = zero4();
#pragma unroll
      for (int ks = 0; ks < 6; ++ks)
        acc = __builtin_amdgcn_mfma_f32_16x16x32_bf16(A[ks], bq[ks], acc, 0, 0, 0);
      if (tc < T) {
#pragma unroll
        for (int r = 0; r < 4; ++r) {
          const int o = m * 16 + g * 4 + r;
          if (o < DIM)
            out[(size_t)(b * DIM + o) * LL + t0 + tc] = acc[r] + bo[o];
        }
      }
    }
  }
}

extern "C" void kernel_launch(void* const* d_in, const int* in_sizes, int n_in,
                              void* d_out, int out_size, void* d_ws, size_t ws_size,
                              hipStream_t stream) {
  const float* fmap = (const float*)d_in[0];
  const float* Wq   = (const float*)d_in[1];
  const float* Wkv  = (const float*)d_in[2];
  const float* Wo   = (const float*)d_in[3];
  const float* bo   = (const float*)d_in[4];
  float* o = (float*)d_out;

  unsigned short* wqkv_b = (unsigned short*)d_ws;        // 576*192 bf16
  unsigned short* wo_h   = wqkv_b + 576 * 192;           // 192*192 bf16

  const int prep_elems = 576 * 192 + 192 * 192;          // 147,456
  hipLaunchKernelGGL(la_prep, dim3((prep_elems + 1023) / 1024), dim3(1024), 0,
                     stream, Wq, Wkv, Wo, wqkv_b, wo_h);
  hipLaunchKernelGGL(la_main, dim3(B * NCH), dim3(512), 0, stream,
                     fmap, wqkv_b, wo_h, bo, o);
}